// Round 7
// baseline (516.477 us; speedup 1.0000x reference)
//
#include <hip/hip_runtime.h>
#include <hip/hip_bf16.h>

#define N_NODES 100000
#define N_EDGES 1600000
#define BATCH   16384
#define HID     128

#define SHIFT 9
#define BSZ   512
#define NB    196
#define EPB   8192

typedef __attribute__((ext_vector_type(8))) short bf16x8;
typedef __attribute__((ext_vector_type(4))) float fx4;
typedef __attribute__((ext_vector_type(2))) float fx2;

__device__ inline short f2bf(float f) {
    unsigned u = __builtin_bit_cast(unsigned, f);
    unsigned r = (u + 0x7FFF + ((u >> 16) & 1)) >> 16;
    return (short)r;
}
__device__ inline float bf2f(short s) {
    unsigned u = ((unsigned)(unsigned short)s) << 16;
    return __builtin_bit_cast(float, u);
}

// ---------------- CSR build: bucketed two-pass (unchanged) ----------------

__global__ __launch_bounds__(256) void k_bhist(const int* __restrict__ dst,
                                               int* __restrict__ bcnt, int E) {
    __shared__ int lh[NB];
    int t = threadIdx.x;
    for (int j = t; j < NB; j += 256) lh[j] = 0;
    __syncthreads();
    int base = blockIdx.x * 4096;
    int n = min(4096, E - base);
    for (int i = t; i < n; i += 256) atomicAdd(&lh[dst[base + i] >> SHIFT], 1);
    __syncthreads();
    for (int j = t; j < NB; j += 256)
        if (lh[j]) atomicAdd(&bcnt[j], lh[j]);
}

__global__ void k_bscan(const int* __restrict__ bcnt, int* __restrict__ bbase,
                        int* __restrict__ bcur, int* __restrict__ offsets) {
    __shared__ int sh[256];
    int t = threadIdx.x;
    int c = (t < NB) ? bcnt[t] : 0;
    sh[t] = c;
    __syncthreads();
    for (int off = 1; off < 256; off <<= 1) {
        int v = 0;
        if (t >= off) v = sh[t - off];
        __syncthreads();
        if (t >= off) sh[t] += v;
        __syncthreads();
    }
    int incl = sh[t];
    int excl = incl - c;
    if (t < NB) { bbase[t] = excl; bcur[t] = excl; }
    if (t == NB - 1) { bbase[NB] = incl; offsets[N_NODES] = incl; }
}

__global__ __launch_bounds__(256) void k_passA(
    const int* __restrict__ edge, int* __restrict__ bcur,
    unsigned* __restrict__ tmp, int E) {
    __shared__ unsigned staged[EPB];
    __shared__ unsigned char bkt[EPB];
    __shared__ int lh[NB], lstart[NB], gbase[NB], lcur[NB];
    int t = threadIdx.x;
    int base = blockIdx.x * EPB;
    int n = min(EPB, E - base);
    for (int j = t; j < NB; j += 256) lh[j] = 0;
    __syncthreads();
    for (int i = t; i < n; i += 256)
        atomicAdd(&lh[edge[E + base + i] >> SHIFT], 1);
    __syncthreads();
    if (t == 0) {
        int run = 0;
        for (int b = 0; b < NB; ++b) { lstart[b] = run; run += lh[b]; }
    }
    __syncthreads();
    if (t < NB) {
        gbase[t] = atomicAdd(&bcur[t], lh[t]);
        lcur[t] = lstart[t];
    }
    __syncthreads();
    for (int i = t; i < n; i += 256) {
        int s = edge[base + i];
        int d = edge[E + base + i];
        int b = d >> SHIFT;
        unsigned p = (unsigned)s | ((unsigned)(d & (BSZ - 1)) << 17);
        int pos = atomicAdd(&lcur[b], 1);
        staged[pos] = p;
        bkt[pos] = (unsigned char)b;
    }
    __syncthreads();
    for (int i = t; i < n; i += 256) {
        int b = bkt[i];
        tmp[gbase[b] + (i - lstart[b])] = staged[i];
    }
}

__global__ __launch_bounds__(256) void k_passB(
    const unsigned* __restrict__ tmp, const int* __restrict__ bbase,
    int* __restrict__ offsets, float* __restrict__ dinv,
    int* __restrict__ col) {
    __shared__ int lh[BSZ];
    __shared__ int lsum[256];
    int b = blockIdx.x, t = threadIdx.x;
    int begin = bbase[b], end = bbase[b + 1];
    lh[t] = 0; lh[t + 256] = 0;
    __syncthreads();
    for (int i = begin + t; i < end; i += 256)
        atomicAdd(&lh[tmp[i] >> 17], 1);
    __syncthreads();
    int c0 = lh[2 * t], c1 = lh[2 * t + 1];
    int tsum = c0 + c1;
    lsum[t] = tsum;
    __syncthreads();
    for (int off = 1; off < 256; off <<= 1) {
        int v = 0;
        if (t >= off) v = lsum[t - off];
        __syncthreads();
        if (t >= off) lsum[t] += v;
        __syncthreads();
    }
    int texcl = lsum[t] - tsum;
    int node0 = (b << SHIFT) + 2 * t;
    if (node0 < N_NODES) {
        offsets[node0] = begin + texcl;
        dinv[node0] = rsqrtf((float)c0 + 1.f);
    }
    if (node0 + 1 < N_NODES) {
        offsets[node0 + 1] = begin + texcl + c0;
        dinv[node0 + 1] = rsqrtf((float)c1 + 1.f);
    }
    __syncthreads();
    lh[2 * t] = texcl;
    lh[2 * t + 1] = texcl + c0;
    __syncthreads();
    for (int i = begin + t; i < end; i += 1024) {
        int i1 = i + 256, i2 = i + 512, i3 = i + 768;
        unsigned p0 = tmp[i];
        unsigned p1 = (i1 < end) ? tmp[i1] : 0u;
        unsigned p2 = (i2 < end) ? tmp[i2] : 0u;
        unsigned p3 = (i3 < end) ? tmp[i3] : 0u;
        int pos0 = begin + atomicAdd(&lh[p0 >> 17], 1);
        col[pos0] = (int)(p0 & 0x1FFFFu);
        if (i1 < end) { int q = begin + atomicAdd(&lh[p1 >> 17], 1); col[q] = (int)(p1 & 0x1FFFFu); }
        if (i2 < end) { int q = begin + atomicAdd(&lh[p2 >> 17], 1); col[q] = (int)(p2 & 0x1FFFFu); }
        if (i3 < end) { int q = begin + atomicAdd(&lh[p3 >> 17], 1); col[q] = (int)(p3 & 0x1FFFFu); }
    }
}

// ---------------- weight prep: fp32 W[k][n] -> bf16 hi/lo, transposed [n][k] ----------------

__global__ void k_prepW(const float* __restrict__ Wc0, const float* __restrict__ Wc1,
                        const float* __restrict__ Wc2, const float* __restrict__ Wp,
                        const float* __restrict__ Ww,
                        short* __restrict__ outH, short* __restrict__ outL) {
    int c = blockIdx.x;
    const float* src;
    int koff = 0;
    if (c == 0) src = Wc0;
    else if (c == 1) src = Wc1;
    else if (c == 2) src = Wc2;
    else if (c < 6) { src = Wp; koff = (c - 3) * 128; }
    else { src = Ww; koff = (c - 6) * 128; }
    short* dh = outH + c * 16384;
    short* dl = outL + c * 16384;
    for (int i = threadIdx.x; i < 16384; i += 256) {
        int k = i >> 7, n = i & 127;
        float v = src[(size_t)(koff + k) * 128 + n];
        short h = f2bf(v);
        short l = f2bf(v - bf2f(h));
        dh[n * 128 + k] = h;
        dl[n * 128 + k] = l;
    }
}

// ---------------- split helper ----------------

__device__ inline void split8(const float* p, bf16x8& h8, bf16x8& l8) {
    float4 va = *(const float4*)p;
    float4 vb = *(const float4*)(p + 4);
    float vv[8] = {va.x, va.y, va.z, va.w, vb.x, vb.y, vb.z, vb.w};
#pragma unroll
    for (int j = 0; j < 8; ++j) {
        short hb = f2bf(vv[j]);
        h8[j] = hb;
        l8[j] = f2bf(vv[j] - bf2f(hb));
    }
}

// ---------------- epilogue helper: LDS transpose -> coalesced 16B stores ----------------
// wave tile 16 rows x 64 cols; Ls = per-wave [16][72] bf16 region.

__device__ inline void epi_store(short* __restrict__ Lw, const fx4* acc,
                                 const float* __restrict__ scale,
                                 short* __restrict__ outb,
                                 int rowBase, int colBase, int M) {
    int lane = threadIdx.x & 63;
    int l15 = lane & 15;
    int rq = (lane >> 4) << 2;
#pragma unroll
    for (int fc = 0; fc < 4; ++fc) {
#pragma unroll
        for (int rg = 0; rg < 4; ++rg) {
            int rl = rq + rg;
            int r = rowBase + rl;
            float sc = (r < M) ? scale[r] : 0.f;
            Lw[rl * 72 + fc * 16 + l15] = f2bf(acc[fc][rg] * sc);
        }
    }
    __syncthreads();
    int rrow = lane >> 2, rchunk = lane & 3;
    int r = rowBase + rrow;
    if (r < M) {
        const uint4 v0 = *(const uint4*)&Lw[rrow * 72 + rchunk * 16];
        const uint4 v1 = *(const uint4*)&Lw[rrow * 72 + rchunk * 16 + 8];
        uint4* dst = (uint4*)&outb[((size_t)r << 7) + colBase + rchunk * 16];
        dst[0] = v0;
        dst[1] = v1;
    }
}

// ---------------- layer-1 GEMM: fp32 A, in-register split, bf16 out ----------------
// grid (1563, 2); block 64 rows x 64 cols; 4 waves of 16 rows x 64 cols.

__global__ __launch_bounds__(256) void k_rgemm32(
    const float* __restrict__ A, const short* __restrict__ WTh,
    const short* __restrict__ WTl, short* __restrict__ outb,
    const float* __restrict__ scale, int M) {
    __shared__ short Ls[4][16 * 72];
    int t = threadIdx.x;
    int lane = t & 63, wave = t >> 6;
    int l15 = lane & 15;
    int kq = (lane >> 4) << 3;
    int rowBase = (blockIdx.x << 6) + (wave << 4);
    int colBase = blockIdx.y << 6;
    int r0i = rowBase + l15;

    fx4 acc[4];
#pragma unroll
    for (int j = 0; j < 4; ++j) {
        acc[j][0] = 0.f; acc[j][1] = 0.f; acc[j][2] = 0.f; acc[j][3] = 0.f;
    }

#pragma unroll
    for (int ks = 0; ks < 4; ++ks) {
        int ko = (ks << 5) + kq;
        bf16x8 a0h = {0,0,0,0,0,0,0,0}, a0l = {0,0,0,0,0,0,0,0};
        if (r0i < M) split8(&A[(size_t)r0i * 128 + ko], a0h, a0l);
#pragma unroll
        for (int fc = 0; fc < 4; ++fc) {
            int c = colBase + (fc << 4) + l15;
            size_t bo = ((size_t)c << 7) + ko;
            bf16x8 bh = *(const bf16x8*)&WTh[bo];
            bf16x8 bl = *(const bf16x8*)&WTl[bo];
            acc[fc] = __builtin_amdgcn_mfma_f32_16x16x32_bf16(a0h, bh, acc[fc], 0, 0, 0);
            acc[fc] = __builtin_amdgcn_mfma_f32_16x16x32_bf16(a0h, bl, acc[fc], 0, 0, 0);
            acc[fc] = __builtin_amdgcn_mfma_f32_16x16x32_bf16(a0l, bh, acc[fc], 0, 0, 0);
        }
    }
    epi_store(Ls[wave], acc, scale, outb, rowBase, colBase, M);
}

// ---------------- conv GEMM: split-bf16 A, bf16 out ----------------

__global__ __launch_bounds__(256) void k_rgemm(
    const short* __restrict__ Ah, const short* __restrict__ Al,
    const short* __restrict__ WTh, const short* __restrict__ WTl,
    short* __restrict__ outb, const float* __restrict__ scale, int M) {
    __shared__ short Ls[4][16 * 72];
    int t = threadIdx.x;
    int lane = t & 63, wave = t >> 6;
    int l15 = lane & 15;
    int kq = (lane >> 4) << 3;
    int rowBase = (blockIdx.x << 6) + (wave << 4);
    int colBase = blockIdx.y << 6;
    int r0i = rowBase + l15;
    long long ar0 = (r0i < M) ? (long long)r0i : -1;

    fx4 acc[4];
#pragma unroll
    for (int j = 0; j < 4; ++j) {
        acc[j][0] = 0.f; acc[j][1] = 0.f; acc[j][2] = 0.f; acc[j][3] = 0.f;
    }

#pragma unroll
    for (int ks = 0; ks < 4; ++ks) {
        int ko = (ks << 5) + kq;
        bf16x8 a0h = {0,0,0,0,0,0,0,0}, a0l = {0,0,0,0,0,0,0,0};
        if (ar0 >= 0) {
            a0h = *(const bf16x8*)&Ah[ar0 * 128 + ko];
            a0l = *(const bf16x8*)&Al[ar0 * 128 + ko];
        }
#pragma unroll
        for (int fc = 0; fc < 4; ++fc) {
            int c = colBase + (fc << 4) + l15;
            size_t bo = ((size_t)c << 7) + ko;
            bf16x8 bh = *(const bf16x8*)&WTh[bo];
            bf16x8 bl = *(const bf16x8*)&WTl[bo];
            acc[fc] = __builtin_amdgcn_mfma_f32_16x16x32_bf16(a0h, bh, acc[fc], 0, 0, 0);
            acc[fc] = __builtin_amdgcn_mfma_f32_16x16x32_bf16(a0h, bl, acc[fc], 0, 0, 0);
            acc[fc] = __builtin_amdgcn_mfma_f32_16x16x32_bf16(a0l, bh, acc[fc], 0, 0, 0);
        }
    }
    epi_store(Ls[wave], acc, scale, outb, rowBase, colBase, M);
}

// ---------------- aggregation (unchanged) ----------------

__device__ inline void addrow(uint4 u, fx2* a) {
    a[0] += (fx2){__builtin_bit_cast(float, u.x << 16),
                  __builtin_bit_cast(float, u.x & 0xFFFF0000u)};
    a[1] += (fx2){__builtin_bit_cast(float, u.y << 16),
                  __builtin_bit_cast(float, u.y & 0xFFFF0000u)};
    a[2] += (fx2){__builtin_bit_cast(float, u.z << 16),
                  __builtin_bit_cast(float, u.z & 0xFFFF0000u)};
    a[3] += (fx2){__builtin_bit_cast(float, u.w << 16),
                  __builtin_bit_cast(float, u.w & 0xFFFF0000u)};
}

__device__ inline void agg_body(const short* __restrict__ h,
                                const int* __restrict__ col,
                                const int* __restrict__ offs,
                                const float* __restrict__ dinv,
                                const float* __restrict__ bias,
                                short* __restrict__ xoh,
                                short* __restrict__ xol,
                                int v, int orow) {
    int lane = threadIdx.x & 63;
    int g = lane >> 4;
    int li = lane & 15;
    int beg = offs[v], end = offs[v + 1];
    float dv = dinv[v];
    fx2 a4[4] = {{0.f,0.f},{0.f,0.f},{0.f,0.f},{0.f,0.f}};
    if (g == 0)
        addrow(*(const uint4*)&h[(size_t)v * 128 + (li << 3)], a4);
    int e = beg + g;
    for (; e + 12 < end; e += 16) {
        int s0 = col[e], s1 = col[e + 4], s2 = col[e + 8], s3 = col[e + 12];
        uint4 u0 = *(const uint4*)&h[(size_t)s0 * 128 + (li << 3)];
        uint4 u1 = *(const uint4*)&h[(size_t)s1 * 128 + (li << 3)];
        uint4 u2 = *(const uint4*)&h[(size_t)s2 * 128 + (li << 3)];
        uint4 u3 = *(const uint4*)&h[(size_t)s3 * 128 + (li << 3)];
        addrow(u0, a4); addrow(u1, a4); addrow(u2, a4); addrow(u3, a4);
    }
    for (; e < end; e += 4)
        addrow(*(const uint4*)&h[(size_t)col[e] * 128 + (li << 3)], a4);

    float a[8];
#pragma unroll
    for (int j = 0; j < 4; ++j) { a[2 * j] = a4[j][0]; a[2 * j + 1] = a4[j][1]; }
#pragma unroll
    for (int off = 16; off <= 32; off <<= 1)
#pragma unroll
        for (int j = 0; j < 8; ++j) a[j] += __shfl_xor(a[j], off);
    if (g == 0) {
        bf16x8 hh, ll;
#pragma unroll
        for (int j = 0; j < 8; ++j) {
            float o = fmaxf(fmaf(a[j], dv, bias[(li << 3) + j]), 0.f);
            short hb = f2bf(o);
            hh[j] = hb;
            ll[j] = f2bf(o - bf2f(hb));
        }
        *(bf16x8*)&xoh[(size_t)orow * 128 + (li << 3)] = hh;
        *(bf16x8*)&xol[(size_t)orow * 128 + (li << 3)] = ll;
    }
}

__global__ __launch_bounds__(256) void k_agg(
    const short* __restrict__ h, const int* __restrict__ col,
    const int* __restrict__ offs, const float* __restrict__ dinv,
    const float* __restrict__ bias, short* __restrict__ xoh,
    short* __restrict__ xol, int n) {
    int v = (blockIdx.x << 2) + (threadIdx.x >> 6);
    if (v >= n) return;
    agg_body(h, col, offs, dinv, bias, xoh, xol, v, v);
}

__global__ __launch_bounds__(256) void k_agg3(
    const short* __restrict__ h, const int* __restrict__ col,
    const int* __restrict__ offs, const float* __restrict__ dinv,
    const float* __restrict__ bias, short* __restrict__ xoh,
    short* __restrict__ xol, const int* __restrict__ sidx,
    const int* __restrict__ tidx) {
    int i = (blockIdx.x << 2) + (threadIdx.x >> 6);
    if (i >= 2 * BATCH) return;
    int v = (i < BATCH) ? sidx[i] : tidx[i - BATCH];
    agg_body(h, col, offs, dinv, bias, xoh, xol, v, i);
}

// ---------------- fused P/Q projection + dot ----------------
// 1024 blocks x 16 pairs. waves 0-1: P (sidx, Wp, bp) col halves; waves 2-3: Q.
// Stage P,Q fp32 rows in LDS, then in-block rowwise dot -> out.

__global__ __launch_bounds__(256) void k_pq(
    const short* __restrict__ a1h, const short* __restrict__ a1l,
    const short* __restrict__ a2h, const short* __restrict__ a2l,
    const short* __restrict__ x3h, const short* __restrict__ x3l,
    const short* __restrict__ wtH, const short* __restrict__ wtL,
    const int* __restrict__ sidx, const int* __restrict__ tidx,
    const float* __restrict__ bp, const float* __restrict__ bw,
    float* __restrict__ out) {
    __shared__ float Ps[16][132];
    __shared__ float Qs[16][132];
    int t = threadIdx.x;
    int lane = t & 63, wave = t >> 6;
    int isQ = wave >> 1, wn = wave & 1;
    int l15 = lane & 15;
    int kq = (lane >> 4) << 3;
    int pairBase = blockIdx.x << 4;
    int colBase = wn << 6;
    const int* gidx = isQ ? tidx : sidx;
    const float* bias = isQ ? bw : bp;
    int r0 = pairBase + l15;
    long long n0 = (long long)gidx[r0];

    fx4 acc[4];
#pragma unroll
    for (int j = 0; j < 4; ++j) {
        acc[j][0] = 0.f; acc[j][1] = 0.f; acc[j][2] = 0.f; acc[j][3] = 0.f;
    }

#pragma unroll
    for (int c = 0; c < 3; ++c) {
        const short* Ah = (c == 0) ? a1h : (c == 1) ? a2h : x3h;
        const short* Al = (c == 0) ? a1l : (c == 1) ? a2l : x3l;
        long long b0 = (c == 2) ? (long long)(r0 + (isQ << 14)) : n0;
        const short* Bh = wtH + (size_t)(3 + isQ * 3 + c) * 16384;
        const short* Bl = wtL + (size_t)(3 + isQ * 3 + c) * 16384;
#pragma unroll
        for (int ks = 0; ks < 4; ++ks) {
            int ko = (ks << 5) + kq;
            bf16x8 a0h = *(const bf16x8*)&Ah[b0 * 128 + ko];
            bf16x8 a0l = *(const bf16x8*)&Al[b0 * 128 + ko];
#pragma unroll
            for (int fc = 0; fc < 4; ++fc) {
                int cc = colBase + (fc << 4) + l15;
                size_t bo = ((size_t)cc << 7) + ko;
                bf16x8 bh = *(const bf16x8*)&Bh[bo];
                bf16x8 bl = *(const bf16x8*)&Bl[bo];
                acc[fc] = __builtin_amdgcn_mfma_f32_16x16x32_bf16(a0h, bh, acc[fc], 0, 0, 0);
                acc[fc] = __builtin_amdgcn_mfma_f32_16x16x32_bf16(a0h, bl, acc[fc], 0, 0, 0);
                acc[fc] = __builtin_amdgcn_mfma_f32_16x16x32_bf16(a0l, bh, acc[fc], 0, 0, 0);
            }
        }
    }

    int rq = (lane >> 4) << 2;
    float (*dst)[132] = isQ ? Qs : Ps;
#pragma unroll
    for (int fc = 0; fc < 4; ++fc) {
        int cg = colBase + (fc << 4) + l15;
        float bv = bias[cg];
#pragma unroll
        for (int rg = 0; rg < 4; ++rg)
            dst[rq + rg][cg] = acc[fc][rg] + bv;
    }
    __syncthreads();

    int p = t >> 4, seg = t & 15;
    const float* pr = &Ps[p][seg * 8];
    const float* qr = &Qs[p][seg * 8];
    float s = 0.f;
#pragma unroll
    for (int j = 0; j < 8; ++j) s += pr[j] * qr[j];
    s += __shfl_xor(s, 1);
    s += __shfl_xor(s, 2);
    s += __shfl_xor(s, 4);
    s += __shfl_xor(s, 8);
    if (seg == 0) out[pairBase + p] = s;
}

// ---------------- launch ----------------

extern "C" void kernel_launch(void* const* d_in, const int* in_sizes, int n_in,
                              void* d_out, int out_size, void* d_ws, size_t ws_size,
                              hipStream_t stream) {
    const float* x    = (const float*)d_in[0];
    const int*   edge = (const int*)d_in[1];
    const int*   sidx = (const int*)d_in[2];
    const int*   tidx = (const int*)d_in[3];
    const float* Wc0  = (const float*)d_in[4];
    const float* bc0  = (const float*)d_in[5];
    const float* Wc1  = (const float*)d_in[6];
    const float* bc1  = (const float*)d_in[7];
    const float* Wc2  = (const float*)d_in[8];
    const float* bc2  = (const float*)d_in[9];
    const float* Ww   = (const float*)d_in[10];
    const float* bw   = (const float*)d_in[11];
    const float* Wp   = (const float*)d_in[12];
    const float* bp   = (const float*)d_in[13];
    float* out = (float*)d_out;

    char* base = (char*)d_ws;
    size_t off = 0;
    auto alloc = [&](size_t bytes) -> char* {
        char* p = base + off;
        off = (off + bytes + 255) & ~(size_t)255;
        return p;
    };
    const size_t HSZ = (size_t)N_NODES * HID * sizeof(short);     // 25.6 MB
    const size_t XSZ = (size_t)2 * BATCH * HID * sizeof(short);   // 8.4 MB
    short* a1h  = (short*)alloc(HSZ);
    short* a1l  = (short*)alloc(HSZ);
    short* a2h  = (short*)alloc(HSZ);
    short* a2l  = (short*)alloc(HSZ);
    short* x3h  = (short*)alloc(XSZ);
    short* x3l  = (short*)alloc(XSZ);
    short* hbf  = (short*)alloc(HSZ);
    int*   offsets = (int*)alloc((size_t)(N_NODES + 1) * sizeof(int));
    int*   colArr  = (int*)alloc((size_t)N_EDGES * sizeof(int));
    unsigned* tmp  = (unsigned*)alloc((size_t)N_EDGES * sizeof(unsigned));
    float* dinv    = (float*)alloc((size_t)N_NODES * sizeof(float));
    int*   bcnt    = (int*)alloc(256 * sizeof(int));
    int*   bbase   = (int*)alloc(256 * sizeof(int));
    int*   bcur    = (int*)alloc(256 * sizeof(int));
    short* wtH     = (short*)alloc((size_t)9 * 16384 * sizeof(short));
    short* wtL     = (short*)alloc((size_t)9 * 16384 * sizeof(short));
    (void)ws_size; (void)in_sizes; (void)n_in; (void)out_size;

    // ---- CSR build ----
    hipMemsetAsync(bcnt, 0, NB * sizeof(int), stream);
    k_bhist<<<(N_EDGES + 4095) / 4096, 256, 0, stream>>>(edge + N_EDGES, bcnt, N_EDGES);
    k_bscan<<<1, 256, 0, stream>>>(bcnt, bbase, bcur, offsets);
    k_passA<<<(N_EDGES + EPB - 1) / EPB, 256, 0, stream>>>(edge, bcur, tmp, N_EDGES);
    k_passB<<<NB, 256, 0, stream>>>(tmp, bbase, offsets, dinv, colArr);

    // ---- weight prep ----
    k_prepW<<<9, 256, 0, stream>>>(Wc0, Wc1, Wc2, Wp, Ww, wtH, wtL);

    const dim3 gemmGrid((N_NODES + 63) / 64, 2);   // 1563 x 2
    const int aggGrid  = (N_NODES + 3) / 4;        // 25000
    const int agg3Grid = (2 * BATCH) / 4;          // 8192
#define WT(c) (wtH + (c) * 16384), (wtL + (c) * 16384)

    // ---- layer 1 ----
    k_rgemm32<<<gemmGrid, 256, 0, stream>>>(x, WT(0), hbf, dinv, N_NODES);
    k_agg<<<aggGrid, 256, 0, stream>>>(hbf, colArr, offsets, dinv, bc0, a1h, a1l, N_NODES);

    // ---- layer 2 ----
    k_rgemm<<<gemmGrid, 256, 0, stream>>>(a1h, a1l, WT(1), hbf, dinv, N_NODES);
    k_agg<<<aggGrid, 256, 0, stream>>>(hbf, colArr, offsets, dinv, bc1, a2h, a2l, N_NODES);

    // ---- layer 3 (batch nodes only) ----
    k_rgemm<<<gemmGrid, 256, 0, stream>>>(a2h, a2l, WT(2), hbf, dinv, N_NODES);
    k_agg3<<<agg3Grid, 256, 0, stream>>>(hbf, colArr, offsets, dinv, bc2, x3h, x3l, sidx, tidx);

    // ---- fused P/Q + dot ----
    k_pq<<<BATCH / 16, 256, 0, stream>>>(a1h, a1l, a2h, a2l, x3h, x3l, wtH, wtL,
                                         sidx, tidx, bp, bw, out);
}

// Round 8
// 431.638 us; speedup vs baseline: 1.1966x; 1.1966x over previous
//
#include <hip/hip_runtime.h>
#include <hip/hip_bf16.h>

#define N_NODES 100000
#define N_EDGES 1600000
#define BATCH   16384
#define HID     128

#define SHIFT 9
#define BSZ   512
#define NB    196
#define EPB   8192

typedef __attribute__((ext_vector_type(8))) short bf16x8;
typedef __attribute__((ext_vector_type(4))) float fx4;
typedef __attribute__((ext_vector_type(2))) float fx2;

__device__ inline short f2bf(float f) {
    unsigned u = __builtin_bit_cast(unsigned, f);
    unsigned r = (u + 0x7FFF + ((u >> 16) & 1)) >> 16;
    return (short)r;
}
__device__ inline float bf2f(short s) {
    unsigned u = ((unsigned)(unsigned short)s) << 16;
    return __builtin_bit_cast(float, u);
}

// ---------------- CSR build: bucketed two-pass (unchanged) ----------------

__global__ __launch_bounds__(256) void k_bhist(const int* __restrict__ dst,
                                               int* __restrict__ bcnt, int E) {
    __shared__ int lh[NB];
    int t = threadIdx.x;
    for (int j = t; j < NB; j += 256) lh[j] = 0;
    __syncthreads();
    int base = blockIdx.x * 4096;
    int n = min(4096, E - base);
    for (int i = t; i < n; i += 256) atomicAdd(&lh[dst[base + i] >> SHIFT], 1);
    __syncthreads();
    for (int j = t; j < NB; j += 256)
        if (lh[j]) atomicAdd(&bcnt[j], lh[j]);
}

__global__ void k_bscan(const int* __restrict__ bcnt, int* __restrict__ bbase,
                        int* __restrict__ bcur, int* __restrict__ offsets) {
    __shared__ int sh[256];
    int t = threadIdx.x;
    int c = (t < NB) ? bcnt[t] : 0;
    sh[t] = c;
    __syncthreads();
    for (int off = 1; off < 256; off <<= 1) {
        int v = 0;
        if (t >= off) v = sh[t - off];
        __syncthreads();
        if (t >= off) sh[t] += v;
        __syncthreads();
    }
    int incl = sh[t];
    int excl = incl - c;
    if (t < NB) { bbase[t] = excl; bcur[t] = excl; }
    if (t == NB - 1) { bbase[NB] = incl; offsets[N_NODES] = incl; }
}

__global__ __launch_bounds__(256) void k_passA(
    const int* __restrict__ edge, int* __restrict__ bcur,
    unsigned* __restrict__ tmp, int E) {
    __shared__ unsigned staged[EPB];
    __shared__ unsigned char bkt[EPB];
    __shared__ int lh[NB], lstart[NB], gbase[NB], lcur[NB];
    int t = threadIdx.x;
    int base = blockIdx.x * EPB;
    int n = min(EPB, E - base);
    for (int j = t; j < NB; j += 256) lh[j] = 0;
    __syncthreads();
    for (int i = t; i < n; i += 256)
        atomicAdd(&lh[edge[E + base + i] >> SHIFT], 1);
    __syncthreads();
    if (t == 0) {
        int run = 0;
        for (int b = 0; b < NB; ++b) { lstart[b] = run; run += lh[b]; }
    }
    __syncthreads();
    if (t < NB) {
        gbase[t] = atomicAdd(&bcur[t], lh[t]);
        lcur[t] = lstart[t];
    }
    __syncthreads();
    for (int i = t; i < n; i += 256) {
        int s = edge[base + i];
        int d = edge[E + base + i];
        int b = d >> SHIFT;
        unsigned p = (unsigned)s | ((unsigned)(d & (BSZ - 1)) << 17);
        int pos = atomicAdd(&lcur[b], 1);
        staged[pos] = p;
        bkt[pos] = (unsigned char)b;
    }
    __syncthreads();
    for (int i = t; i < n; i += 256) {
        int b = bkt[i];
        tmp[gbase[b] + (i - lstart[b])] = staged[i];
    }
}

__global__ __launch_bounds__(256) void k_passB(
    const unsigned* __restrict__ tmp, const int* __restrict__ bbase,
    int* __restrict__ offsets, float* __restrict__ dinv,
    int* __restrict__ col) {
    __shared__ int lh[BSZ];
    __shared__ int lsum[256];
    int b = blockIdx.x, t = threadIdx.x;
    int begin = bbase[b], end = bbase[b + 1];
    lh[t] = 0; lh[t + 256] = 0;
    __syncthreads();
    for (int i = begin + t; i < end; i += 256)
        atomicAdd(&lh[tmp[i] >> 17], 1);
    __syncthreads();
    int c0 = lh[2 * t], c1 = lh[2 * t + 1];
    int tsum = c0 + c1;
    lsum[t] = tsum;
    __syncthreads();
    for (int off = 1; off < 256; off <<= 1) {
        int v = 0;
        if (t >= off) v = lsum[t - off];
        __syncthreads();
        if (t >= off) lsum[t] += v;
        __syncthreads();
    }
    int texcl = lsum[t] - tsum;
    int node0 = (b << SHIFT) + 2 * t;
    if (node0 < N_NODES) {
        offsets[node0] = begin + texcl;
        dinv[node0] = rsqrtf((float)c0 + 1.f);
    }
    if (node0 + 1 < N_NODES) {
        offsets[node0 + 1] = begin + texcl + c0;
        dinv[node0 + 1] = rsqrtf((float)c1 + 1.f);
    }
    __syncthreads();
    lh[2 * t] = texcl;
    lh[2 * t + 1] = texcl + c0;
    __syncthreads();
    for (int i = begin + t; i < end; i += 1024) {
        int i1 = i + 256, i2 = i + 512, i3 = i + 768;
        unsigned p0 = tmp[i];
        unsigned p1 = (i1 < end) ? tmp[i1] : 0u;
        unsigned p2 = (i2 < end) ? tmp[i2] : 0u;
        unsigned p3 = (i3 < end) ? tmp[i3] : 0u;
        int pos0 = begin + atomicAdd(&lh[p0 >> 17], 1);
        col[pos0] = (int)(p0 & 0x1FFFFu);
        if (i1 < end) { int q = begin + atomicAdd(&lh[p1 >> 17], 1); col[q] = (int)(p1 & 0x1FFFFu); }
        if (i2 < end) { int q = begin + atomicAdd(&lh[p2 >> 17], 1); col[q] = (int)(p2 & 0x1FFFFu); }
        if (i3 < end) { int q = begin + atomicAdd(&lh[p3 >> 17], 1); col[q] = (int)(p3 & 0x1FFFFu); }
    }
}

// ---------------- weight prep: fp32 W[k][n] -> interleaved hi/lo, transposed ----------------
// chunk c layout per col n: 256 shorts; k-chunk c16: [hi e0..e7][lo e0..e7] at n*256+c16*16.

__global__ void k_prepW(const float* __restrict__ Wc0, const float* __restrict__ Wc1,
                        const float* __restrict__ Wc2, const float* __restrict__ Wp,
                        const float* __restrict__ Ww, short* __restrict__ wI) {
    int c = blockIdx.x;
    const float* src;
    int koff = 0;
    if (c == 0) src = Wc0;
    else if (c == 1) src = Wc1;
    else if (c == 2) src = Wc2;
    else if (c < 6) { src = Wp; koff = (c - 3) * 128; }
    else { src = Ww; koff = (c - 6) * 128; }
    short* d = wI + (size_t)c * 32768;
    for (int i = threadIdx.x; i < 16384; i += 256) {
        int k = i >> 7, n = i & 127;
        float v = src[(size_t)(koff + k) * 128 + n];
        short h = f2bf(v);
        short l = f2bf(v - bf2f(h));
        int c16 = k >> 3, j = k & 7;
        d[n * 256 + c16 * 16 + j] = h;
        d[n * 256 + c16 * 16 + 8 + j] = l;
    }
}

// ---------------- split helper ----------------

__device__ inline void split8(const float* p, bf16x8& h8, bf16x8& l8) {
    float4 va = *(const float4*)p;
    float4 vb = *(const float4*)(p + 4);
    float vv[8] = {va.x, va.y, va.z, va.w, vb.x, vb.y, vb.z, vb.w};
#pragma unroll
    for (int j = 0; j < 8; ++j) {
        short hb = f2bf(vv[j]);
        h8[j] = hb;
        l8[j] = f2bf(vv[j] - bf2f(hb));
    }
}

// ---------------- layer-1 GEMM: fp32 A (in-reg split), interleaved W, bf16 out ----------------
// round-6 shape: 4 waves 2x2, wave 32 rows x 64 cols, block 64x128, grid 1563.

__global__ __launch_bounds__(256) void k_rgemm32(
    const float* __restrict__ A, const short* __restrict__ WI,
    short* __restrict__ outb, const float* __restrict__ scale, int M) {
    int t = threadIdx.x;
    int lane = t & 63, wave = t >> 6;
    int wm = wave >> 1, wn = wave & 1;
    int l15 = lane & 15;
    int g = lane >> 4;
    int kq = g << 3;
    int g16 = g << 4;
    int rowBase = blockIdx.x << 6;
    int colBase = wn << 6;
    int r0i = rowBase + (wm << 5) + l15;
    int r1i = r0i + 16;

    fx4 acc[2][4];
#pragma unroll
    for (int i = 0; i < 2; ++i)
#pragma unroll
        for (int j = 0; j < 4; ++j) {
            acc[i][j][0] = 0.f; acc[i][j][1] = 0.f;
            acc[i][j][2] = 0.f; acc[i][j][3] = 0.f;
        }

#pragma unroll
    for (int ks = 0; ks < 4; ++ks) {
        int ko = (ks << 5) + kq;
        int co = (ks << 6) + g16;
        bf16x8 a0h = {0,0,0,0,0,0,0,0}, a0l = {0,0,0,0,0,0,0,0};
        bf16x8 a1h = {0,0,0,0,0,0,0,0}, a1l = {0,0,0,0,0,0,0,0};
        if (r0i < M) split8(&A[(size_t)r0i * 128 + ko], a0h, a0l);
        if (r1i < M) split8(&A[(size_t)r1i * 128 + ko], a1h, a1l);
#pragma unroll
        for (int fc = 0; fc < 4; ++fc) {
            int c = colBase + (fc << 4) + l15;
            const short* bp = &WI[((size_t)c << 8) + co];
            bf16x8 bh = *(const bf16x8*)bp;
            bf16x8 bl = *(const bf16x8*)(bp + 8);
            acc[0][fc] = __builtin_amdgcn_mfma_f32_16x16x32_bf16(a0h, bh, acc[0][fc], 0, 0, 0);
            acc[0][fc] = __builtin_amdgcn_mfma_f32_16x16x32_bf16(a0h, bl, acc[0][fc], 0, 0, 0);
            acc[0][fc] = __builtin_amdgcn_mfma_f32_16x16x32_bf16(a0l, bh, acc[0][fc], 0, 0, 0);
            acc[1][fc] = __builtin_amdgcn_mfma_f32_16x16x32_bf16(a1h, bh, acc[1][fc], 0, 0, 0);
            acc[1][fc] = __builtin_amdgcn_mfma_f32_16x16x32_bf16(a1h, bl, acc[1][fc], 0, 0, 0);
            acc[1][fc] = __builtin_amdgcn_mfma_f32_16x16x32_bf16(a1l, bh, acc[1][fc], 0, 0, 0);
        }
    }

    int rq = (lane >> 4) << 2;
#pragma unroll
    for (int fr = 0; fr < 2; ++fr) {
        int rb = rowBase + (wm << 5) + (fr << 4) + rq;
#pragma unroll
        for (int rg = 0; rg < 4; ++rg) {
            int r = rb + rg;
            if (r >= M) continue;
            float sc = scale[r];
#pragma unroll
            for (int fc = 0; fc < 4; ++fc) {
                int cg = colBase + (fc << 4) + l15;
                outb[((size_t)r << 7) + cg] = f2bf(acc[fr][fc][rg] * sc);
            }
        }
    }
}

// ---------------- conv GEMM: interleaved A, interleaved W, bf16 out ----------------

__global__ __launch_bounds__(256) void k_rgemm(
    const short* __restrict__ AI, const short* __restrict__ WI,
    short* __restrict__ outb, const float* __restrict__ scale, int M) {
    int t = threadIdx.x;
    int lane = t & 63, wave = t >> 6;
    int wm = wave >> 1, wn = wave & 1;
    int l15 = lane & 15;
    int g16 = (lane >> 4) << 4;
    int rowBase = blockIdx.x << 6;
    int colBase = wn << 6;
    int r0i = rowBase + (wm << 5) + l15;
    int r1i = r0i + 16;
    bool v0 = r0i < M, v1 = r1i < M;

    fx4 acc[2][4];
#pragma unroll
    for (int i = 0; i < 2; ++i)
#pragma unroll
        for (int j = 0; j < 4; ++j) {
            acc[i][j][0] = 0.f; acc[i][j][1] = 0.f;
            acc[i][j][2] = 0.f; acc[i][j][3] = 0.f;
        }

#pragma unroll
    for (int ks = 0; ks < 4; ++ks) {
        int co = (ks << 6) + g16;
        bf16x8 a0h = {0,0,0,0,0,0,0,0}, a0l = {0,0,0,0,0,0,0,0};
        bf16x8 a1h = {0,0,0,0,0,0,0,0}, a1l = {0,0,0,0,0,0,0,0};
        if (v0) {
            const short* ap = &AI[((size_t)r0i << 8) + co];
            a0h = *(const bf16x8*)ap;
            a0l = *(const bf16x8*)(ap + 8);
        }
        if (v1) {
            const short* ap = &AI[((size_t)r1i << 8) + co];
            a1h = *(const bf16x8*)ap;
            a1l = *(const bf16x8*)(ap + 8);
        }
#pragma unroll
        for (int fc = 0; fc < 4; ++fc) {
            int c = colBase + (fc << 4) + l15;
            const short* bp = &WI[((size_t)c << 8) + co];
            bf16x8 bh = *(const bf16x8*)bp;
            bf16x8 bl = *(const bf16x8*)(bp + 8);
            acc[0][fc] = __builtin_amdgcn_mfma_f32_16x16x32_bf16(a0h, bh, acc[0][fc], 0, 0, 0);
            acc[0][fc] = __builtin_amdgcn_mfma_f32_16x16x32_bf16(a0h, bl, acc[0][fc], 0, 0, 0);
            acc[0][fc] = __builtin_amdgcn_mfma_f32_16x16x32_bf16(a0l, bh, acc[0][fc], 0, 0, 0);
            acc[1][fc] = __builtin_amdgcn_mfma_f32_16x16x32_bf16(a1h, bh, acc[1][fc], 0, 0, 0);
            acc[1][fc] = __builtin_amdgcn_mfma_f32_16x16x32_bf16(a1h, bl, acc[1][fc], 0, 0, 0);
            acc[1][fc] = __builtin_amdgcn_mfma_f32_16x16x32_bf16(a1l, bh, acc[1][fc], 0, 0, 0);
        }
    }

    int rq = (lane >> 4) << 2;
#pragma unroll
    for (int fr = 0; fr < 2; ++fr) {
        int rb = rowBase + (wm << 5) + (fr << 4) + rq;
#pragma unroll
        for (int rg = 0; rg < 4; ++rg) {
            int r = rb + rg;
            if (r >= M) continue;
            float sc = scale[r];
#pragma unroll
            for (int fc = 0; fc < 4; ++fc) {
                int cg = colBase + (fc << 4) + l15;
                outb[((size_t)r << 7) + cg] = f2bf(acc[fr][fc][rg] * sc);
            }
        }
    }
}

// ---------------- aggregation: reads bf16 h, writes interleaved hi/lo ----------------

__device__ inline void addrow(uint4 u, fx2* a) {
    a[0] += (fx2){__builtin_bit_cast(float, u.x << 16),
                  __builtin_bit_cast(float, u.x & 0xFFFF0000u)};
    a[1] += (fx2){__builtin_bit_cast(float, u.y << 16),
                  __builtin_bit_cast(float, u.y & 0xFFFF0000u)};
    a[2] += (fx2){__builtin_bit_cast(float, u.z << 16),
                  __builtin_bit_cast(float, u.z & 0xFFFF0000u)};
    a[3] += (fx2){__builtin_bit_cast(float, u.w << 16),
                  __builtin_bit_cast(float, u.w & 0xFFFF0000u)};
}

__device__ inline void agg_body(const short* __restrict__ h,
                                const int* __restrict__ col,
                                const int* __restrict__ offs,
                                const float* __restrict__ dinv,
                                const float* __restrict__ bias,
                                short* __restrict__ xoI,
                                int v, int orow) {
    int lane = threadIdx.x & 63;
    int g = lane >> 4;
    int li = lane & 15;
    int beg = offs[v], end = offs[v + 1];
    float dv = dinv[v];
    fx2 a4[4] = {{0.f,0.f},{0.f,0.f},{0.f,0.f},{0.f,0.f}};
    if (g == 0)
        addrow(*(const uint4*)&h[(size_t)v * 128 + (li << 3)], a4);
    int e = beg + g;
    for (; e + 12 < end; e += 16) {
        int s0 = col[e], s1 = col[e + 4], s2 = col[e + 8], s3 = col[e + 12];
        uint4 u0 = *(const uint4*)&h[(size_t)s0 * 128 + (li << 3)];
        uint4 u1 = *(const uint4*)&h[(size_t)s1 * 128 + (li << 3)];
        uint4 u2 = *(const uint4*)&h[(size_t)s2 * 128 + (li << 3)];
        uint4 u3 = *(const uint4*)&h[(size_t)s3 * 128 + (li << 3)];
        addrow(u0, a4); addrow(u1, a4); addrow(u2, a4); addrow(u3, a4);
    }
    for (; e < end; e += 4)
        addrow(*(const uint4*)&h[(size_t)col[e] * 128 + (li << 3)], a4);

    float a[8];
#pragma unroll
    for (int j = 0; j < 4; ++j) { a[2 * j] = a4[j][0]; a[2 * j + 1] = a4[j][1]; }
#pragma unroll
    for (int off = 16; off <= 32; off <<= 1)
#pragma unroll
        for (int j = 0; j < 8; ++j) a[j] += __shfl_xor(a[j], off);
    if (g == 0) {
        bf16x8 hh, ll;
#pragma unroll
        for (int j = 0; j < 8; ++j) {
            float o = fmaxf(fmaf(a[j], dv, bias[(li << 3) + j]), 0.f);
            short hb = f2bf(o);
            hh[j] = hb;
            ll[j] = f2bf(o - bf2f(hb));
        }
        short* dst = &xoI[((size_t)orow << 8) + (li << 4)];
        *(bf16x8*)dst = hh;
        *(bf16x8*)(dst + 8) = ll;
    }
}

__global__ __launch_bounds__(256) void k_agg(
    const short* __restrict__ h, const int* __restrict__ col,
    const int* __restrict__ offs, const float* __restrict__ dinv,
    const float* __restrict__ bias, short* __restrict__ xoI, int n) {
    int v = (blockIdx.x << 2) + (threadIdx.x >> 6);
    if (v >= n) return;
    agg_body(h, col, offs, dinv, bias, xoI, v, v);
}

__global__ __launch_bounds__(256) void k_agg3(
    const short* __restrict__ h, const int* __restrict__ col,
    const int* __restrict__ offs, const float* __restrict__ dinv,
    const float* __restrict__ bias, short* __restrict__ xoI,
    const int* __restrict__ sidx, const int* __restrict__ tidx) {
    int i = (blockIdx.x << 2) + (threadIdx.x >> 6);
    if (i >= 2 * BATCH) return;
    int v = (i < BATCH) ? sidx[i] : tidx[i - BATCH];
    agg_body(h, col, offs, dinv, bias, xoI, v, i);
}

// ---------------- fused P/Q projection + dot ----------------
// 512 blocks x 32 pairs; waves 0-1 = P col-halves, waves 2-3 = Q; LDS dot.

__global__ __launch_bounds__(256) void k_pq(
    const short* __restrict__ a1I, const short* __restrict__ a2I,
    const short* __restrict__ x3I, const short* __restrict__ wI,
    const int* __restrict__ sidx, const int* __restrict__ tidx,
    const float* __restrict__ bp, const float* __restrict__ bw,
    float* __restrict__ out) {
    __shared__ float Ps[32][132];
    __shared__ float Qs[32][132];
    int t = threadIdx.x;
    int lane = t & 63, wave = t >> 6;
    int isQ = wave >> 1, wn = wave & 1;
    int l15 = lane & 15;
    int g16 = (lane >> 4) << 4;
    int pairBase = blockIdx.x << 5;
    int colBase = wn << 6;
    const int* gidx = isQ ? tidx : sidx;
    const float* bias = isQ ? bw : bp;
    int r0i = pairBase + l15;
    int r1i = r0i + 16;
    long long n0 = (long long)gidx[r0i];
    long long n1 = (long long)gidx[r1i];

    fx4 acc[2][4];
#pragma unroll
    for (int i = 0; i < 2; ++i)
#pragma unroll
        for (int j = 0; j < 4; ++j) {
            acc[i][j][0] = 0.f; acc[i][j][1] = 0.f;
            acc[i][j][2] = 0.f; acc[i][j][3] = 0.f;
        }

#pragma unroll
    for (int c = 0; c < 3; ++c) {
        const short* AI = (c == 0) ? a1I : (c == 1) ? a2I : x3I;
        long long b0 = (c == 2) ? (long long)(r0i + (isQ << 14)) : n0;
        long long b1 = (c == 2) ? (long long)(r1i + (isQ << 14)) : n1;
        const short* WB = wI + (size_t)(3 + isQ * 3 + c) * 32768;
#pragma unroll
        for (int ks = 0; ks < 4; ++ks) {
            int co = (ks << 6) + g16;
            const short* ap0 = &AI[(b0 << 8) + co];
            const short* ap1 = &AI[(b1 << 8) + co];
            bf16x8 a0h = *(const bf16x8*)ap0;
            bf16x8 a0l = *(const bf16x8*)(ap0 + 8);
            bf16x8 a1h = *(const bf16x8*)ap1;
            bf16x8 a1l = *(const bf16x8*)(ap1 + 8);
#pragma unroll
            for (int fc = 0; fc < 4; ++fc) {
                int cc = colBase + (fc << 4) + l15;
                const short* bpp = &WB[((size_t)cc << 8) + co];
                bf16x8 bh = *(const bf16x8*)bpp;
                bf16x8 bl = *(const bf16x8*)(bpp + 8);
                acc[0][fc] = __builtin_amdgcn_mfma_f32_16x16x32_bf16(a0h, bh, acc[0][fc], 0, 0, 0);
                acc[0][fc] = __builtin_amdgcn_mfma_f32_16x16x32_bf16(a0h, bl, acc[0][fc], 0, 0, 0);
                acc[0][fc] = __builtin_amdgcn_mfma_f32_16x16x32_bf16(a0l, bh, acc[0][fc], 0, 0, 0);
                acc[1][fc] = __builtin_amdgcn_mfma_f32_16x16x32_bf16(a1h, bh, acc[1][fc], 0, 0, 0);
                acc[1][fc] = __builtin_amdgcn_mfma_f32_16x16x32_bf16(a1h, bl, acc[1][fc], 0, 0, 0);
                acc[1][fc] = __builtin_amdgcn_mfma_f32_16x16x32_bf16(a1l, bh, acc[1][fc], 0, 0, 0);
            }
        }
    }

    int rq = (lane >> 4) << 2;
    float (*dst)[132] = isQ ? Qs : Ps;
#pragma unroll
    for (int fr = 0; fr < 2; ++fr) {
#pragma unroll
        for (int fc = 0; fc < 4; ++fc) {
            int cg = colBase + (fc << 4) + l15;
            float bv = bias[cg];
#pragma unroll
            for (int rg = 0; rg < 4; ++rg)
                dst[(fr << 4) + rq + rg][cg] = acc[fr][fc][rg] + bv;
        }
    }
    __syncthreads();

    int p = t >> 3, seg = t & 7;
    const float* pr = &Ps[p][seg * 16];
    const float* qr = &Qs[p][seg * 16];
    float s = 0.f;
#pragma unroll
    for (int j = 0; j < 16; ++j) s += pr[j] * qr[j];
    s += __shfl_xor(s, 1);
    s += __shfl_xor(s, 2);
    s += __shfl_xor(s, 4);
    if (seg == 0) out[pairBase + p] = s;
}

// ---------------- launch ----------------

extern "C" void kernel_launch(void* const* d_in, const int* in_sizes, int n_in,
                              void* d_out, int out_size, void* d_ws, size_t ws_size,
                              hipStream_t stream) {
    const float* x    = (const float*)d_in[0];
    const int*   edge = (const int*)d_in[1];
    const int*   sidx = (const int*)d_in[2];
    const int*   tidx = (const int*)d_in[3];
    const float* Wc0  = (const float*)d_in[4];
    const float* bc0  = (const float*)d_in[5];
    const float* Wc1  = (const float*)d_in[6];
    const float* bc1  = (const float*)d_in[7];
    const float* Wc2  = (const float*)d_in[8];
    const float* bc2  = (const float*)d_in[9];
    const float* Ww   = (const float*)d_in[10];
    const float* bw   = (const float*)d_in[11];
    const float* Wp   = (const float*)d_in[12];
    const float* bp   = (const float*)d_in[13];
    float* out = (float*)d_out;

    char* base = (char*)d_ws;
    size_t off = 0;
    auto alloc = [&](size_t bytes) -> char* {
        char* p = base + off;
        off = (off + bytes + 255) & ~(size_t)255;
        return p;
    };
    const size_t ISZ = (size_t)N_NODES * 256 * sizeof(short);      // 51.2 MB
    const size_t XSZ = (size_t)2 * BATCH * 256 * sizeof(short);    // 16.8 MB
    short* a1I  = (short*)alloc(ISZ);
    short* a2I  = (short*)alloc(ISZ);
    short* x3I  = (short*)alloc(XSZ);
    short* hbf  = (short*)alloc((size_t)N_NODES * HID * sizeof(short));
    int*   offsets = (int*)alloc((size_t)(N_NODES + 1) * sizeof(int));
    int*   colArr  = (int*)alloc((size_t)N_EDGES * sizeof(int));
    unsigned* tmp  = (unsigned*)alloc((size_t)N_EDGES * sizeof(unsigned));
    float* dinv    = (float*)alloc((size_t)N_NODES * sizeof(float));
    int*   bcnt    = (int*)alloc(256 * sizeof(int));
    int*   bbase   = (int*)alloc(256 * sizeof(int));
    int*   bcur    = (int*)alloc(256 * sizeof(int));
    short* wI      = (short*)alloc((size_t)9 * 32768 * sizeof(short));
    (void)ws_size; (void)in_sizes; (void)n_in; (void)out_size;

    // ---- CSR build ----
    hipMemsetAsync(bcnt, 0, NB * sizeof(int), stream);
    k_bhist<<<(N_EDGES + 4095) / 4096, 256, 0, stream>>>(edge + N_EDGES, bcnt, N_EDGES);
    k_bscan<<<1, 256, 0, stream>>>(bcnt, bbase, bcur, offsets);
    k_passA<<<(N_EDGES + EPB - 1) / EPB, 256, 0, stream>>>(edge, bcur, tmp, N_EDGES);
    k_passB<<<NB, 256, 0, stream>>>(tmp, bbase, offsets, dinv, colArr);

    // ---- weight prep ----
    k_prepW<<<9, 256, 0, stream>>>(Wc0, Wc1, Wc2, Wp, Ww, wI);

    const int gridN   = (N_NODES + 63) / 64;   // 1563
    const int aggGrid  = (N_NODES + 3) / 4;    // 25000
    const int agg3Grid = (2 * BATCH) / 4;      // 8192
#define WI(c) (wI + (size_t)(c) * 32768)

    // ---- layer 1 ----
    k_rgemm32<<<gridN, 256, 0, stream>>>(x, WI(0), hbf, dinv, N_NODES);
    k_agg<<<aggGrid, 256, 0, stream>>>(hbf, colArr, offsets, dinv, bc0, a1I, N_NODES);

    // ---- layer 2 ----
    k_rgemm<<<gridN, 256, 0, stream>>>(a1I, WI(1), hbf, dinv, N_NODES);
    k_agg<<<aggGrid, 256, 0, stream>>>(hbf, colArr, offsets, dinv, bc1, a2I, N_NODES);

    // ---- layer 3 (batch nodes only) ----
    k_rgemm<<<gridN, 256, 0, stream>>>(a2I, WI(2), hbf, dinv, N_NODES);
    k_agg3<<<agg3Grid, 256, 0, stream>>>(hbf, colArr, offsets, dinv, bc2, x3I, sidx, tidx);

    // ---- fused P/Q + dot ----
    k_pq<<<BATCH / 32, 256, 0, stream>>>(a1I, a2I, x3I, wI, sidx, tidx, bp, bw, out);
}

// Round 10
// 379.462 us; speedup vs baseline: 1.3611x; 1.1375x over previous
//
#include <hip/hip_runtime.h>
#include <hip/hip_bf16.h>

#define N_NODES 100000
#define N_EDGES 1600000
#define BATCH   16384
#define HID     128

#define SHIFT 9
#define BSZ   512
#define NB    196
#define EPB   8192

typedef __attribute__((ext_vector_type(8))) short bf16x8;
typedef __attribute__((ext_vector_type(4))) float fx4;
typedef __attribute__((ext_vector_type(2))) float fx2;

__device__ inline short f2bf(float f) {
    unsigned u = __builtin_bit_cast(unsigned, f);
    unsigned r = (u + 0x7FFF + ((u >> 16) & 1)) >> 16;
    return (short)r;
}
__device__ inline float bf2f(short s) {
    unsigned u = ((unsigned)(unsigned short)s) << 16;
    return __builtin_bit_cast(float, u);
}

// ---------------- CSR build: bucketed two-pass (unchanged) ----------------

__global__ __launch_bounds__(256) void k_bhist(const int* __restrict__ dst,
                                               int* __restrict__ bcnt, int E) {
    __shared__ int lh[NB];
    int t = threadIdx.x;
    for (int j = t; j < NB; j += 256) lh[j] = 0;
    __syncthreads();
    int base = blockIdx.x * 4096;
    int n = min(4096, E - base);
    for (int i = t; i < n; i += 256) atomicAdd(&lh[dst[base + i] >> SHIFT], 1);
    __syncthreads();
    for (int j = t; j < NB; j += 256)
        if (lh[j]) atomicAdd(&bcnt[j], lh[j]);
}

__global__ void k_bscan(const int* __restrict__ bcnt, int* __restrict__ bbase,
                        int* __restrict__ bcur, int* __restrict__ offsets) {
    __shared__ int sh[256];
    int t = threadIdx.x;
    int c = (t < NB) ? bcnt[t] : 0;
    sh[t] = c;
    __syncthreads();
    for (int off = 1; off < 256; off <<= 1) {
        int v = 0;
        if (t >= off) v = sh[t - off];
        __syncthreads();
        if (t >= off) sh[t] += v;
        __syncthreads();
    }
    int incl = sh[t];
    int excl = incl - c;
    if (t < NB) { bbase[t] = excl; bcur[t] = excl; }
    if (t == NB - 1) { bbase[NB] = incl; offsets[N_NODES] = incl; }
}

__global__ __launch_bounds__(256) void k_passA(
    const int* __restrict__ edge, int* __restrict__ bcur,
    unsigned* __restrict__ tmp, int E) {
    __shared__ unsigned staged[EPB];
    __shared__ unsigned char bkt[EPB];
    __shared__ int lh[NB], lstart[NB], gbase[NB], lcur[NB];
    int t = threadIdx.x;
    int base = blockIdx.x * EPB;
    int n = min(EPB, E - base);
    for (int j = t; j < NB; j += 256) lh[j] = 0;
    __syncthreads();
    for (int i = t; i < n; i += 256)
        atomicAdd(&lh[edge[E + base + i] >> SHIFT], 1);
    __syncthreads();
    if (t == 0) {
        int run = 0;
        for (int b = 0; b < NB; ++b) { lstart[b] = run; run += lh[b]; }
    }
    __syncthreads();
    if (t < NB) {
        gbase[t] = atomicAdd(&bcur[t], lh[t]);
        lcur[t] = lstart[t];
    }
    __syncthreads();
    for (int i = t; i < n; i += 256) {
        int s = edge[base + i];
        int d = edge[E + base + i];
        int b = d >> SHIFT;
        unsigned p = (unsigned)s | ((unsigned)(d & (BSZ - 1)) << 17);
        int pos = atomicAdd(&lcur[b], 1);
        staged[pos] = p;
        bkt[pos] = (unsigned char)b;
    }
    __syncthreads();
    for (int i = t; i < n; i += 256) {
        int b = bkt[i];
        tmp[gbase[b] + (i - lstart[b])] = staged[i];
    }
}

__global__ __launch_bounds__(256) void k_passB(
    const unsigned* __restrict__ tmp, const int* __restrict__ bbase,
    int* __restrict__ offsets, float* __restrict__ dinv,
    int* __restrict__ col) {
    __shared__ int lh[BSZ];
    __shared__ int lsum[256];
    int b = blockIdx.x, t = threadIdx.x;
    int begin = bbase[b], end = bbase[b + 1];
    lh[t] = 0; lh[t + 256] = 0;
    __syncthreads();
    for (int i = begin + t; i < end; i += 256)
        atomicAdd(&lh[tmp[i] >> 17], 1);
    __syncthreads();
    int c0 = lh[2 * t], c1 = lh[2 * t + 1];
    int tsum = c0 + c1;
    lsum[t] = tsum;
    __syncthreads();
    for (int off = 1; off < 256; off <<= 1) {
        int v = 0;
        if (t >= off) v = lsum[t - off];
        __syncthreads();
        if (t >= off) lsum[t] += v;
        __syncthreads();
    }
    int texcl = lsum[t] - tsum;
    int node0 = (b << SHIFT) + 2 * t;
    if (node0 < N_NODES) {
        offsets[node0] = begin + texcl;
        dinv[node0] = rsqrtf((float)c0 + 1.f);
    }
    if (node0 + 1 < N_NODES) {
        offsets[node0 + 1] = begin + texcl + c0;
        dinv[node0 + 1] = rsqrtf((float)c1 + 1.f);
    }
    __syncthreads();
    lh[2 * t] = texcl;
    lh[2 * t + 1] = texcl + c0;
    __syncthreads();
    for (int i = begin + t; i < end; i += 1024) {
        int i1 = i + 256, i2 = i + 512, i3 = i + 768;
        unsigned p0 = tmp[i];
        unsigned p1 = (i1 < end) ? tmp[i1] : 0u;
        unsigned p2 = (i2 < end) ? tmp[i2] : 0u;
        unsigned p3 = (i3 < end) ? tmp[i3] : 0u;
        int pos0 = begin + atomicAdd(&lh[p0 >> 17], 1);
        col[pos0] = (int)(p0 & 0x1FFFFu);
        if (i1 < end) { int q = begin + atomicAdd(&lh[p1 >> 17], 1); col[q] = (int)(p1 & 0x1FFFFu); }
        if (i2 < end) { int q = begin + atomicAdd(&lh[p2 >> 17], 1); col[q] = (int)(p2 & 0x1FFFFu); }
        if (i3 < end) { int q = begin + atomicAdd(&lh[p3 >> 17], 1); col[q] = (int)(p3 & 0x1FFFFu); }
    }
}

// ---------------- weight prep: fp32 W[k][n] -> interleaved hi/lo, transposed ----------------

__global__ void k_prepW(const float* __restrict__ Wc0, const float* __restrict__ Wc1,
                        const float* __restrict__ Wc2, const float* __restrict__ Wp,
                        const float* __restrict__ Ww, short* __restrict__ wI) {
    int c = blockIdx.x;
    const float* src;
    int koff = 0;
    if (c == 0) src = Wc0;
    else if (c == 1) src = Wc1;
    else if (c == 2) src = Wc2;
    else if (c < 6) { src = Wp; koff = (c - 3) * 128; }
    else { src = Ww; koff = (c - 6) * 128; }
    short* d = wI + (size_t)c * 32768;
    for (int i = threadIdx.x; i < 16384; i += 256) {
        int k = i >> 7, n = i & 127;
        float v = src[(size_t)(koff + k) * 128 + n];
        short h = f2bf(v);
        short l = f2bf(v - bf2f(h));
        int c16 = k >> 3, j = k & 7;
        d[n * 256 + c16 * 16 + j] = h;
        d[n * 256 + c16 * 16 + 8 + j] = l;
    }
}

// ---------------- pipelined persistent-block GEMM ----------------
// A row = 512 bytes (fp32 x OR interleaved bf16 hi/lo). Tile = 64 rows = 32 KB.
// Double-buffered global_load_lds staging, XOR-swizzled (source + ds_read sides).
// B (one 128x128 W, interleaved) lives in registers per wave.

__device__ inline void stage_tile(char* __restrict__ buf, const char* __restrict__ A,
                                  int tile, int maxRow, int t) {
    int rowBase = tile << 6;
#pragma unroll
    for (int j = 0; j < 8; ++j) {
        int s = (j << 8) + t;            // 16B slot 0..2047
        int row = s >> 5;
        int cpos = s & 31;
        int c = cpos ^ (row & 7);        // pre-swizzled source chunk
        int gr = rowBase + row;
        if (gr > maxRow) gr = maxRow;
        const char* src = A + ((size_t)gr << 9) + (c << 4);
        char* dst = buf + (((j << 8) + (t & 192)) << 4);   // wave-uniform base
        __builtin_amdgcn_global_load_lds(
            (const __attribute__((address_space(1))) unsigned*)src,
            (__attribute__((address_space(3))) unsigned*)dst, 16, 0, 0);
    }
}

template<int ISF32>
__global__ __launch_bounds__(256) void k_sgemm(
    const char* __restrict__ A, const short* __restrict__ WI,
    short* __restrict__ outb, const float* __restrict__ scale, int M) {
    __shared__ __align__(16) char lds[65536];
    int t = threadIdx.x;
    int lane = t & 63, wave = t >> 6;
    int wm = wave >> 1, wn = wave & 1;
    int l15 = lane & 15, g = lane >> 4;
    int colBase = wn << 6;
    int rq = g << 2;

    // ---- B into registers (once) ----
    bf16x8 Bh[4][4], Bl[4][4];
#pragma unroll
    for (int ks = 0; ks < 4; ++ks)
#pragma unroll
        for (int fc = 0; fc < 4; ++fc) {
            int c = colBase + (fc << 4) + l15;
            const short* bp = &WI[((size_t)c << 8) + (((ks << 2) + g) << 4)];
            Bh[ks][fc] = *(const bf16x8*)bp;
            Bl[ks][fc] = *(const bf16x8*)(bp + 8);
        }

    int nT = (M + 63) >> 6;
    int maxRow = M - 1;
    int tile = blockIdx.x;
    if (tile < nT) stage_tile(lds, A, tile, maxRow, t);
    int cur = 0;

    for (; tile < nT; tile += gridDim.x) {
        __syncthreads();                       // drains vmcnt -> buf[cur] ready
        int nxt = tile + gridDim.x;
        if (nxt < nT) stage_tile(lds + ((cur ^ 1) << 15), A, nxt, maxRow, t);
        char* buf = lds + (cur << 15);

        fx4 acc[2][4];
#pragma unroll
        for (int i = 0; i < 2; ++i)
#pragma unroll
            for (int j = 0; j < 4; ++j) {
                acc[i][j][0] = 0.f; acc[i][j][1] = 0.f;
                acc[i][j][2] = 0.f; acc[i][j][3] = 0.f;
            }

#pragma unroll
        for (int ks = 0; ks < 4; ++ks) {
            bf16x8 ah[2], al[2];
#pragma unroll
            for (int fr = 0; fr < 2; ++fr) {
                int row = (wm << 5) + (fr << 4) + l15;
                int c0 = (ks << 3) + (g << 1);
                const char* p0 = buf + (row << 9) + ((c0 ^ (row & 7)) << 4);
                const char* p1 = buf + (row << 9) + (((c0 + 1) ^ (row & 7)) << 4);
                if (ISF32) {
                    float v[8];
                    *(float4*)&v[0] = *(const float4*)p0;
                    *(float4*)&v[4] = *(const float4*)p1;
#pragma unroll
                    for (int j = 0; j < 8; ++j) {
                        short hb = f2bf(v[j]);
                        ah[fr][j] = hb;
                        al[fr][j] = f2bf(v[j] - bf2f(hb));
                    }
                } else {
                    ah[fr] = *(const bf16x8*)p0;
                    al[fr] = *(const bf16x8*)p1;
                }
            }
#pragma unroll
            for (int fc = 0; fc < 4; ++fc) {
                acc[0][fc] = __builtin_amdgcn_mfma_f32_16x16x32_bf16(ah[0], Bh[ks][fc], acc[0][fc], 0, 0, 0);
                acc[0][fc] = __builtin_amdgcn_mfma_f32_16x16x32_bf16(ah[0], Bl[ks][fc], acc[0][fc], 0, 0, 0);
                acc[0][fc] = __builtin_amdgcn_mfma_f32_16x16x32_bf16(al[0], Bh[ks][fc], acc[0][fc], 0, 0, 0);
                acc[1][fc] = __builtin_amdgcn_mfma_f32_16x16x32_bf16(ah[1], Bh[ks][fc], acc[1][fc], 0, 0, 0);
                acc[1][fc] = __builtin_amdgcn_mfma_f32_16x16x32_bf16(ah[1], Bl[ks][fc], acc[1][fc], 0, 0, 0);
                acc[1][fc] = __builtin_amdgcn_mfma_f32_16x16x32_bf16(al[1], Bh[ks][fc], acc[1][fc], 0, 0, 0);
            }
        }

        // all waves done reading buf[cur]; prefetch (vmcnt) stays in flight
        __builtin_amdgcn_s_barrier();

        // ---- epilogue via freed buf[cur]: fragment -> row-contiguous stores ----
        short* scr = (short*)buf + wave * 2304;   // [32][72]
        int rowBaseG = tile << 6;
#pragma unroll
        for (int fr = 0; fr < 2; ++fr)
#pragma unroll
            for (int rg = 0; rg < 4; ++rg) {
                int rl = (fr << 4) + rq + rg;
                int R = rowBaseG + (wm << 5) + rl;
                float sc = (R < M) ? scale[R] : 0.f;
#pragma unroll
                for (int fc = 0; fc < 4; ++fc)
                    scr[rl * 72 + (fc << 4) + l15] = f2bf(acc[fr][fc][rg] * sc);
            }
        int rr = lane >> 1, half = lane & 1;
        int R = rowBaseG + (wm << 5) + rr;
        if (R < M) {
            const short* sp = &scr[rr * 72 + (half << 5)];
            short* dp = &outb[((size_t)R << 7) + colBase + (half << 5)];
            ((uint4*)dp)[0] = *(const uint4*)(sp);
            ((uint4*)dp)[1] = *(const uint4*)(sp + 8);
            ((uint4*)dp)[2] = *(const uint4*)(sp + 16);
            ((uint4*)dp)[3] = *(const uint4*)(sp + 24);
        }
        cur ^= 1;
    }
}

// ---------------- aggregation: reads bf16 h, writes interleaved hi/lo ----------------

__device__ inline void addrow(uint4 u, fx2* a) {
    a[0] += (fx2){__builtin_bit_cast(float, u.x << 16),
                  __builtin_bit_cast(float, u.x & 0xFFFF0000u)};
    a[1] += (fx2){__builtin_bit_cast(float, u.y << 16),
                  __builtin_bit_cast(float, u.y & 0xFFFF0000u)};
    a[2] += (fx2){__builtin_bit_cast(float, u.z << 16),
                  __builtin_bit_cast(float, u.z & 0xFFFF0000u)};
    a[3] += (fx2){__builtin_bit_cast(float, u.w << 16),
                  __builtin_bit_cast(float, u.w & 0xFFFF0000u)};
}

__device__ inline void agg_body(const short* __restrict__ h,
                                const int* __restrict__ col,
                                const int* __restrict__ offs,
                                const float* __restrict__ dinv,
                                const float* __restrict__ bias,
                                short* __restrict__ xoI,
                                int v, int orow) {
    int lane = threadIdx.x & 63;
    int g = lane >> 4;
    int li = lane & 15;
    int beg = offs[v], end = offs[v + 1];
    float dv = dinv[v];
    fx2 a4[4] = {{0.f,0.f},{0.f,0.f},{0.f,0.f},{0.f,0.f}};
    if (g == 0)
        addrow(*(const uint4*)&h[(size_t)v * 128 + (li << 3)], a4);
    int e = beg + g;
    for (; e + 12 < end; e += 16) {
        int s0 = col[e], s1 = col[e + 4], s2 = col[e + 8], s3 = col[e + 12];
        uint4 u0 = *(const uint4*)&h[(size_t)s0 * 128 + (li << 3)];
        uint4 u1 = *(const uint4*)&h[(size_t)s1 * 128 + (li << 3)];
        uint4 u2 = *(const uint4*)&h[(size_t)s2 * 128 + (li << 3)];
        uint4 u3 = *(const uint4*)&h[(size_t)s3 * 128 + (li << 3)];
        addrow(u0, a4); addrow(u1, a4); addrow(u2, a4); addrow(u3, a4);
    }
    for (; e < end; e += 4)
        addrow(*(const uint4*)&h[(size_t)col[e] * 128 + (li << 3)], a4);

    float a[8];
#pragma unroll
    for (int j = 0; j < 4; ++j) { a[2 * j] = a4[j][0]; a[2 * j + 1] = a4[j][1]; }
#pragma unroll
    for (int off = 16; off <= 32; off <<= 1)
#pragma unroll
        for (int j = 0; j < 8; ++j) a[j] += __shfl_xor(a[j], off);
    if (g == 0) {
        bf16x8 hh, ll;
#pragma unroll
        for (int j = 0; j < 8; ++j) {
            float o = fmaxf(fmaf(a[j], dv, bias[(li << 3) + j]), 0.f);
            short hb = f2bf(o);
            hh[j] = hb;
            ll[j] = f2bf(o - bf2f(hb));
        }
        short* dst = &xoI[((size_t)orow << 8) + (li << 4)];
        *(bf16x8*)dst = hh;
        *(bf16x8*)(dst + 8) = ll;
    }
}

__global__ __launch_bounds__(256) void k_agg(
    const short* __restrict__ h, const int* __restrict__ col,
    const int* __restrict__ offs, const float* __restrict__ dinv,
    const float* __restrict__ bias, short* __restrict__ xoI, int n) {
    int v = (blockIdx.x << 2) + (threadIdx.x >> 6);
    if (v >= n) return;
    agg_body(h, col, offs, dinv, bias, xoI, v, v);
}

__global__ __launch_bounds__(256) void k_agg3(
    const short* __restrict__ h, const int* __restrict__ col,
    const int* __restrict__ offs, const float* __restrict__ dinv,
    const float* __restrict__ bias, short* __restrict__ xoI,
    const int* __restrict__ sidx, const int* __restrict__ tidx) {
    int i = (blockIdx.x << 2) + (threadIdx.x >> 6);
    if (i >= 2 * BATCH) return;
    int v = (i < BATCH) ? sidx[i] : tidx[i - BATCH];
    agg_body(h, col, offs, dinv, bias, xoI, v, i);
}

// ---------------- fused P/Q projection + dot (unchanged) ----------------

__global__ __launch_bounds__(256) void k_pq(
    const short* __restrict__ a1I, const short* __restrict__ a2I,
    const short* __restrict__ x3I, const short* __restrict__ wI,
    const int* __restrict__ sidx, const int* __restrict__ tidx,
    const float* __restrict__ bp, const float* __restrict__ bw,
    float* __restrict__ out) {
    __shared__ float Ps[32][132];
    __shared__ float Qs[32][132];
    int t = threadIdx.x;
    int lane = t & 63, wave = t >> 6;
    int isQ = wave >> 1, wn = wave & 1;
    int l15 = lane & 15;
    int g16 = (lane >> 4) << 4;
    int pairBase = blockIdx.x << 5;
    int colBase = wn << 6;
    const int* gidx = isQ ? tidx : sidx;
    const float* bias = isQ ? bw : bp;
    int r0i = pairBase + l15;
    int r1i = r0i + 16;
    long long n0 = (long long)gidx[r0i];
    long long n1 = (long long)gidx[r1i];

    fx4 acc[2][4];
#pragma unroll
    for (int i = 0; i < 2; ++i)
#pragma unroll
        for (int j = 0; j < 4; ++j) {
            acc[i][j][0] = 0.f; acc[i][j][1] = 0.f;
            acc[i][j][2] = 0.f; acc[i][j][3] = 0.f;
        }

#pragma unroll
    for (int c = 0; c < 3; ++c) {
        const short* AI = (c == 0) ? a1I : (c == 1) ? a2I : x3I;
        long long b0 = (c == 2) ? (long long)(r0i + (isQ << 14)) : n0;
        long long b1 = (c == 2) ? (long long)(r1i + (isQ << 14)) : n1;
        const short* WB = wI + (size_t)(3 + isQ * 3 + c) * 32768;
#pragma unroll
        for (int ks = 0; ks < 4; ++ks) {
            int co = (ks << 6) + g16;
            const short* ap0 = &AI[(b0 << 8) + co];
            const short* ap1 = &AI[(b1 << 8) + co];
            bf16x8 a0h = *(const bf16x8*)ap0;
            bf16x8 a0l = *(const bf16x8*)(ap0 + 8);
            bf16x8 a1h = *(const bf16x8*)ap1;
            bf16x8 a1l = *(const bf16x8*)(ap1 + 8);
#pragma unroll
            for (int fc = 0; fc < 4; ++fc) {
                int cc = colBase + (fc << 4) + l15;
                const short* bpp = &WB[((size_t)cc << 8) + co];
                bf16x8 bh = *(const bf16x8*)bpp;
                bf16x8 bl = *(const bf16x8*)(bpp + 8);
                acc[0][fc] = __builtin_amdgcn_mfma_f32_16x16x32_bf16(a0h, bh, acc[0][fc], 0, 0, 0);
                acc[0][fc] = __builtin_amdgcn_mfma_f32_16x16x32_bf16(a0h, bl, acc[0][fc], 0, 0, 0);
                acc[0][fc] = __builtin_amdgcn_mfma_f32_16x16x32_bf16(a0l, bh, acc[0][fc], 0, 0, 0);
                acc[1][fc] = __builtin_amdgcn_mfma_f32_16x16x32_bf16(a1h, bh, acc[1][fc], 0, 0, 0);
                acc[1][fc] = __builtin_amdgcn_mfma_f32_16x16x32_bf16(a1h, bl, acc[1][fc], 0, 0, 0);
                acc[1][fc] = __builtin_amdgcn_mfma_f32_16x16x32_bf16(a1l, bh, acc[1][fc], 0, 0, 0);
            }
        }
    }

    int rq = (lane >> 4) << 2;
    float (*dst)[132] = isQ ? Qs : Ps;
#pragma unroll
    for (int fr = 0; fr < 2; ++fr) {
#pragma unroll
        for (int fc = 0; fc < 4; ++fc) {
            int cg = colBase + (fc << 4) + l15;
            float bv = bias[cg];
#pragma unroll
            for (int rg = 0; rg < 4; ++rg)
                dst[(fr << 4) + rq + rg][cg] = acc[fr][fc][rg] + bv;
        }
    }
    __syncthreads();

    int p = t >> 3, seg = t & 7;
    const float* pr = &Ps[p][seg * 16];
    const float* qr = &Qs[p][seg * 16];
    float s = 0.f;
#pragma unroll
    for (int j = 0; j < 16; ++j) s += pr[j] * qr[j];
    s += __shfl_xor(s, 1);
    s += __shfl_xor(s, 2);
    s += __shfl_xor(s, 4);
    if (seg == 0) out[pairBase + p] = s;
}

// ---------------- launch ----------------

extern "C" void kernel_launch(void* const* d_in, const int* in_sizes, int n_in,
                              void* d_out, int out_size, void* d_ws, size_t ws_size,
                              hipStream_t stream) {
    const float* x    = (const float*)d_in[0];
    const int*   edge = (const int*)d_in[1];
    const int*   sidx = (const int*)d_in[2];
    const int*   tidx = (const int*)d_in[3];
    const float* Wc0  = (const float*)d_in[4];
    const float* bc0  = (const float*)d_in[5];
    const float* Wc1  = (const float*)d_in[6];
    const float* bc1  = (const float*)d_in[7];
    const float* Wc2  = (const float*)d_in[8];
    const float* bc2  = (const float*)d_in[9];
    const float* Ww   = (const float*)d_in[10];
    const float* bw   = (const float*)d_in[11];
    const float* Wp   = (const float*)d_in[12];
    const float* bp   = (const float*)d_in[13];
    float* out = (float*)d_out;

    char* base = (char*)d_ws;
    size_t off = 0;
    auto alloc = [&](size_t bytes) -> char* {
        char* p = base + off;
        off = (off + bytes + 255) & ~(size_t)255;
        return p;
    };
    const size_t ISZ = (size_t)N_NODES * 256 * sizeof(short);      // 51.2 MB
    const size_t XSZ = (size_t)2 * BATCH * 256 * sizeof(short);    // 16.8 MB
    short* a1I  = (short*)alloc(ISZ);
    short* a2I  = (short*)alloc(ISZ);
    short* x3I  = (short*)alloc(XSZ);
    short* hbf  = (short*)alloc((size_t)N_NODES * HID * sizeof(short));
    int*   offsets = (int*)alloc((size_t)(N_NODES + 1) * sizeof(int));
    int*   colArr  = (int*)alloc((size_t)N_EDGES * sizeof(int));
    unsigned* tmp  = (unsigned*)alloc((size_t)N_EDGES * sizeof(unsigned));
    float* dinv    = (float*)alloc((size_t)N_NODES * sizeof(float));
    int*   bcnt    = (int*)alloc(256 * sizeof(int));
    int*   bbase   = (int*)alloc(256 * sizeof(int));
    int*   bcur    = (int*)alloc(256 * sizeof(int));
    short* wI      = (short*)alloc((size_t)9 * 32768 * sizeof(short));
    (void)ws_size; (void)in_sizes; (void)n_in; (void)out_size;

    // ---- CSR build ----
    hipMemsetAsync(bcnt, 0, NB * sizeof(int), stream);
    k_bhist<<<(N_EDGES + 4095) / 4096, 256, 0, stream>>>(edge + N_EDGES, bcnt, N_EDGES);
    k_bscan<<<1, 256, 0, stream>>>(bcnt, bbase, bcur, offsets);
    k_passA<<<(N_EDGES + EPB - 1) / EPB, 256, 0, stream>>>(edge, bcur, tmp, N_EDGES);
    k_passB<<<NB, 256, 0, stream>>>(tmp, bbase, offsets, dinv, colArr);

    // ---- weight prep ----
    k_prepW<<<9, 256, 0, stream>>>(Wc0, Wc1, Wc2, Wp, Ww, wI);

    const int aggGrid  = (N_NODES + 3) / 4;    // 25000
    const int agg3Grid = (2 * BATCH) / 4;      // 8192
#define WI(c) (wI + (size_t)(c) * 32768)

    // ---- layer 1 ----
    k_sgemm<1><<<512, 256, 0, stream>>>((const char*)x, WI(0), hbf, dinv, N_NODES);
    k_agg<<<aggGrid, 256, 0, stream>>>(hbf, colArr, offsets, dinv, bc0, a1I, N_NODES);

    // ---- layer 2 ----
    k_sgemm<0><<<512, 256, 0, stream>>>((const char*)a1I, WI(1), hbf, dinv, N_NODES);
    k_agg<<<aggGrid, 256, 0, stream>>>(hbf, colArr, offsets, dinv, bc1, a2I, N_NODES);

    // ---- layer 3 (batch nodes only) ----
    k_sgemm<0><<<512, 256, 0, stream>>>((const char*)a2I, WI(2), hbf, dinv, N_NODES);
    k_agg3<<<agg3Grid, 256, 0, stream>>>(hbf, colArr, offsets, dinv, bc2, x3I, sidx, tidx);

    // ---- fused P/Q + dot ----
    k_pq<<<BATCH / 32, 256, 0, stream>>>(a1I, a2I, x3I, wI, sidx, tidx, bp, bw, out);
}